// Round 7
// baseline (301.623 us; speedup 1.0000x reference)
//
#include <hip/hip_runtime.h>
#include <stdint.h>

#define HB 18                   // coarse bucket = top 13 bits of (bits & 0x7fffffff)
#define SH_SIZE 8192
#define NSAMP 65536
#define SMARG 1912              // sample rank margin; DKW P(fail) <= 2e-112
#define DBITS 22                // band width cap in bit patterns
#define CAND_CAP 8192
#define LIST_CAP 2500000        // band compact list (expected ~2.0M)
#define LBUF_CAP 3072
#define PAIR_CAP 1024
#define PEAK_CAP 512
#define MAX_SPIKE 36
#define AB_BLOCKS 128

// params indices
#define P_ULO   0
#define P_UHI   1
#define P_THRLO 2
#define P_THR   3
#define P_CANDN 4
#define P_LISTN 5
#define P_CB    6
#define P_BINA1 7
#define P_BINA2 8
#define P_RA1   9
#define P_RA2   10
#define P_DONEA 11
#define P_DONEB 12

// ws byte layout (zeroed region first)
#define WS_SHIST  0              // 8192*4 = 32768
#define WS_HISTA  32768          // 2048*4 -> 40960
#define WS_HISTB  40960          // 4096*4 -> 57344
#define WS_PARAMS 57344          // 64 -> 57408
#define WS_ZERO_BYTES 57408
#define WS_CAND   57408          // 8192*4 -> 90176
#define WS_LIST   102400         // 2.5M*4 -> 10,102,400 total

// ---------------- zero control region ----------------
__global__ __launch_bounds__(256) void k_zero(int* __restrict__ ws, int nInts) {
  int j = blockIdx.x * 256 + threadIdx.x;
  if (j < nInts) ws[j] = 0;
}

// ---------------- pad output with -1 ----------------
__global__ __launch_bounds__(256) void k_fillpad(float* __restrict__ out, int n2) {
  int j = blockIdx.x * 256 + threadIdx.x;
  if (j < n2) out[j] = -1.0f;
}

// ---------------- sample 65536 strided elements -> coarse histogram ----------------
__global__ __launch_bounds__(256) void k_sample(const float* __restrict__ x, int N,
                                                int* __restrict__ shist) {
  __shared__ int h[SH_SIZE];
  for (int i = threadIdx.x; i < SH_SIZE; i += 256) h[i] = 0;
  __syncthreads();
  int stride = N / NSAMP; if (stride < 1) stride = 1;
  for (int i = blockIdx.x * 256 + threadIdx.x; i < NSAMP; i += gridDim.x * 256) {
    long long idx = (long long)i * stride;
    if (idx < N) {
      uint32_t u = __float_as_uint(x[idx]) & 0x7fffffffu;
      atomicAdd(&h[u >> HB], 1);
    }
  }
  __syncthreads();
  for (int i = threadIdx.x; i < SH_SIZE; i += 256) {
    int c = h[i];
    if (c) atomicAdd(&shist[i], c);
  }
}

// ---------------- pick band [uLo,uHi) from sample quantiles; thrLo ----------------
__global__ void k_bandsel(const int* __restrict__ shist, int* __restrict__ p) {
  __shared__ int part[256];
  __shared__ int excl[256];
  __shared__ uint32_t uLoS, uHiS;
  int tid = threadIdx.x;
  const int chunk = SH_SIZE / 256;  // 32
  int base = tid * chunk;
  int s = 0;
  for (int w = 0; w < chunk; ++w) s += shist[base + w];
  part[tid] = s;
  __syncthreads();
  if (tid == 0) { int a = 0; for (int i = 0; i < 256; ++i) { excl[i] = a; a += part[i]; } }
  __syncthreads();
  int pre = excl[tid];
  int sA = NSAMP / 2 - SMARG, sB = NSAMP / 2 + SMARG;
  if (pre <= sA && sA < pre + part[tid]) {
    int a = pre;
    for (int w = 0; w < chunk; ++w) {
      int c = shist[base + w];
      if (sA < a + c) { uLoS = (uint32_t)(base + w) << HB; break; }
      a += c;
    }
  }
  if (pre <= sB && sB < pre + part[tid]) {
    int a = pre;
    for (int w = 0; w < chunk; ++w) {
      int c = shist[base + w];
      if (sB < a + c) { uHiS = (uint32_t)(base + w + 1) << HB; break; }
      a += c;
    }
  }
  __syncthreads();
  if (tid == 0) {
    uint32_t uLo = uLoS, uHi = uHiS;
    if (uHi - uLo > (1u << DBITS)) uHi = uLo + (1u << DBITS);
    p[P_ULO] = (int)uLo;
    p[P_UHI] = (int)uHi;
    float vLo = __uint_as_float(uLo);   // vLo <= both median order stats
    p[P_THRLO] = __float_as_int((5.0f * vLo / 0.6745f) * 0.999f);
  }
}

// ---------------- single full pass: countBelow + band compact + candidates ----------------
__device__ inline void m_elem(float f, int idx, uint32_t uLo, uint32_t uHi, float thrLo,
                              int* lbuf, int* lcnt, int* list, int* p, int* cand,
                              int& cb) {
  uint32_t u = __float_as_uint(f) & 0x7fffffffu;
  cb += (u < uLo) ? 1 : 0;
  if (u >= uLo && u < uHi) {
    int d = (int)(u - uLo);
    int id = atomicAdd(lcnt, 1);
    if (id < LBUF_CAP) lbuf[id] = d;
    else { int g = atomicAdd(&p[P_LISTN], 1); if (g < LIST_CAP) list[g] = d; }
  }
  if (__uint_as_float(u) > thrLo) {
    int id = atomicAdd(&p[P_CANDN], 1);
    if (id < CAND_CAP) cand[id] = idx;
  }
}

__global__ __launch_bounds__(256) void k_main(const float* __restrict__ x, int N,
                                              int* __restrict__ p,
                                              int* __restrict__ list,
                                              int* __restrict__ cand) {
  __shared__ int lbuf[LBUF_CAP];
  __shared__ int lcnt;
  __shared__ int lbase;
  __shared__ int red[256];
  if (threadIdx.x == 0) lcnt = 0;
  __syncthreads();
  uint32_t uLo = (uint32_t)p[P_ULO], uHi = (uint32_t)p[P_UHI];
  float thrLo = __int_as_float(p[P_THRLO]);
  int cb = 0;
  int NV = N >> 2;
  int str = gridDim.x * 256;
  const float4* vec = reinterpret_cast<const float4*>(x);
  int j = blockIdx.x * 256 + threadIdx.x;
  for (; j + 7 * str < NV; j += 8 * str) {
    float4 v[8];
#pragma unroll
    for (int k = 0; k < 8; ++k) v[k] = vec[j + k * str];
#pragma unroll
    for (int k = 0; k < 8; ++k) {
      int base = (j + k * str) << 2;
      m_elem(v[k].x, base + 0, uLo, uHi, thrLo, lbuf, &lcnt, list, p, cand, cb);
      m_elem(v[k].y, base + 1, uLo, uHi, thrLo, lbuf, &lcnt, list, p, cand, cb);
      m_elem(v[k].z, base + 2, uLo, uHi, thrLo, lbuf, &lcnt, list, p, cand, cb);
      m_elem(v[k].w, base + 3, uLo, uHi, thrLo, lbuf, &lcnt, list, p, cand, cb);
    }
  }
  for (; j < NV; j += str) {
    float4 a = vec[j];
    int base = j << 2;
    m_elem(a.x, base + 0, uLo, uHi, thrLo, lbuf, &lcnt, list, p, cand, cb);
    m_elem(a.y, base + 1, uLo, uHi, thrLo, lbuf, &lcnt, list, p, cand, cb);
    m_elem(a.z, base + 2, uLo, uHi, thrLo, lbuf, &lcnt, list, p, cand, cb);
    m_elem(a.w, base + 3, uLo, uHi, thrLo, lbuf, &lcnt, list, p, cand, cb);
  }
  if (blockIdx.x == 0 && threadIdx.x == 0) {      // tail (N % 4)
    for (int i = NV << 2; i < N; ++i)
      m_elem(x[i], i, uLo, uHi, thrLo, lbuf, &lcnt, list, p, cand, cb);
  }
  __syncthreads();                                 // lbuf/lcnt final
  int n = lcnt < LBUF_CAP ? lcnt : LBUF_CAP;
  if (threadIdx.x == 0) lbase = atomicAdd(&p[P_LISTN], n);
  red[threadIdx.x] = cb;
  __syncthreads();
  for (int s2 = 128; s2; s2 >>= 1) {
    if (threadIdx.x < s2) red[threadIdx.x] += red[threadIdx.x + s2];
    __syncthreads();
  }
  if (threadIdx.x == 0) atomicAdd(&p[P_CB], red[0]);
  int base = lbase;
  for (int i = threadIdx.x; i < n; i += 256)
    if (base + i < LIST_CAP) list[base + i] = lbuf[i];
}

// ---------------- stage A: 2048-bin hist of d>>11; last block selects both ranks ----------------
__global__ __launch_bounds__(256) void k_stageA(const int* __restrict__ list,
                                                int* __restrict__ p,
                                                int* __restrict__ histA,
                                                long long k1, long long k2) {
  __shared__ int h[2048];
  __shared__ int lastS;
  __shared__ int part[256];
  __shared__ int excl[256];
  for (int i = threadIdx.x; i < 2048; i += 256) h[i] = 0;
  __syncthreads();
  int n = p[P_LISTN]; if (n > LIST_CAP) n = LIST_CAP;
  int str = gridDim.x * 256;
  for (int i = blockIdx.x * 256 + threadIdx.x; i < n; i += str)
    atomicAdd(&h[list[i] >> 11], 1);
  __syncthreads();
  for (int i = threadIdx.x; i < 2048; i += 256) {
    int c = h[i];
    if (c) atomicAdd(&histA[i], c);
  }
  __threadfence();
  if (threadIdx.x == 0) lastS = (atomicAdd(&p[P_DONEA], 1) == (int)gridDim.x - 1);
  __syncthreads();
  if (!lastS) return;
  __threadfence();
  int tid = threadIdx.x;
  long long cb = p[P_CB];
  long long r1l = k1 - cb, r2l = k2 - cb;
  if (r1l < 0) r1l = 0; if (r1l > n - 1) r1l = n - 1;   // sanity clamp (never expected)
  if (r2l < 0) r2l = 0; if (r2l > n - 1) r2l = n - 1;
  int r1 = (int)r1l, r2 = (int)r2l;
  int base = tid * 8;
  int cc[8]; int s = 0;
#pragma unroll
  for (int w = 0; w < 8; ++w) { cc[w] = histA[base + w]; s += cc[w]; }
  part[tid] = s;
  __syncthreads();
  if (tid == 0) { int a = 0; for (int i = 0; i < 256; ++i) { excl[i] = a; a += part[i]; } }
  __syncthreads();
  int pre = excl[tid];
  if (pre <= r1 && r1 < pre + s) {
    int a = pre;
    for (int w = 0; w < 8; ++w) {
      if (r1 < a + cc[w]) { p[P_BINA1] = base + w; p[P_RA1] = r1 - a; break; }
      a += cc[w];
    }
  }
  if (pre <= r2 && r2 < pre + s) {
    int a = pre;
    for (int w = 0; w < 8; ++w) {
      if (r2 < a + cc[w]) { p[P_BINA2] = base + w; p[P_RA2] = r2 - a; break; }
      a += cc[w];
    }
  }
}

// ---------------- stage B: low-11-bit hists for the two selected bins; exact threshold ----------------
__global__ __launch_bounds__(256) void k_stageB(const int* __restrict__ list,
                                                int* __restrict__ p,
                                                int* __restrict__ histB,
                                                float* __restrict__ outThr) {
  __shared__ int h[4096];
  __shared__ int lastS;
  __shared__ int part[256];
  __shared__ int excl[256];
  __shared__ float vres[2];
  for (int i = threadIdx.x; i < 4096; i += 256) h[i] = 0;
  __syncthreads();
  int n = p[P_LISTN]; if (n > LIST_CAP) n = LIST_CAP;
  int binA1 = p[P_BINA1], binA2 = p[P_BINA2];
  int str = gridDim.x * 256;
  for (int i = blockIdx.x * 256 + threadIdx.x; i < n; i += str) {
    int d = list[i];
    int hi = d >> 11, lo = d & 2047;
    if (hi == binA1) atomicAdd(&h[lo], 1);
    if (hi == binA2) atomicAdd(&h[2048 + lo], 1);
  }
  __syncthreads();
  for (int i = threadIdx.x; i < 4096; i += 256) {
    int c = h[i];
    if (c) atomicAdd(&histB[i], c);
  }
  __threadfence();
  if (threadIdx.x == 0) lastS = (atomicAdd(&p[P_DONEB], 1) == (int)gridDim.x - 1);
  __syncthreads();
  if (!lastS) return;
  __threadfence();
  int tid = threadIdx.x;
  uint32_t uLo = (uint32_t)p[P_ULO];
  if (tid < 2) vres[tid] = __uint_as_float(uLo);
  for (int tgt = 0; tgt < 2; ++tgt) {
    __syncthreads();
    const int* hh = histB + tgt * 2048;
    int rank = (tgt == 0) ? p[P_RA1] : p[P_RA2];
    int binA = (tgt == 0) ? binA1 : binA2;
    int base = tid * 8;
    int cc[8]; int s = 0;
#pragma unroll
    for (int w = 0; w < 8; ++w) { cc[w] = hh[base + w]; s += cc[w]; }
    part[tid] = s;
    __syncthreads();
    if (tid == 0) { int a = 0; for (int i = 0; i < 256; ++i) { excl[i] = a; a += part[i]; } }
    __syncthreads();
    int pre = excl[tid];
    if (pre <= rank && rank < pre + s) {
      int a = pre;
      for (int w = 0; w < 8; ++w) {
        if (rank < a + cc[w]) {
          uint32_t bits = uLo + ((uint32_t)binA << 11) + (uint32_t)(base + w);
          vres[tgt] = __uint_as_float(bits);
          break;
        }
        a += cc[w];
      }
    }
  }
  __syncthreads();
  if (tid == 0) {
    float med = 0.5f * (vres[0] + vres[1]);     // np.median: mean of two mid order stats
    float thr = (5.0f * med) / 0.6745f;         // reference float32 expression order
    p[P_THR] = __float_as_int(thr);
    *outThr = thr;                               // out[2*OUT_K]
  }
}

// ---------------- finalize: pairs from candidates, windowed argmax, write peaks ----------------
__device__ static void isort(int* a, int n) {
  for (int i = 1; i < n; ++i) {
    int v = a[i]; int j = i - 1;
    while (j >= 0 && a[j] > v) { a[j + 1] = a[j]; --j; }
    a[j + 1] = v;
  }
}

__device__ inline void eval_pair(const float* __restrict__ x, int p, float thr,
                                 int* pe, int* px, int* ne, int* nx, int* cnt) {
  float a = x[p], b = x[p + 1];
  bool m0 = a > thr, m1 = b > thr;
  if (m0 != m1) {
    int id = atomicAdd(&cnt[m1 ? 0 : 1], 1);
    if (id < PAIR_CAP) (m1 ? pe : px)[id] = p;
  }
  bool q0 = (-a) > thr, q1 = (-b) > thr;       // exact ref form: v=-x, v>thr
  if (q0 != q1) {
    int id = atomicAdd(&cnt[q1 ? 2 : 3], 1);
    if (id < PAIR_CAP) (q1 ? ne : nx)[id] = p;
  }
}

__device__ inline int wave_argmax36(const float* __restrict__ x, int N, int sign,
                                    int e, int lane) {
  float val = -INFINITY;
  int wi = lane;
  if (lane < MAX_SPIKE) {
    int idx = e + lane; if (idx > N - 1) idx = N - 1;   // ref: clip(entry+w, 0, N-1)
    float v = x[idx];
    val = (sign < 0) ? -v : v;
  }
  for (int off = 32; off; off >>= 1) {                  // tie -> smaller w (first max)
    float ov = __shfl_xor(val, off);
    int owi = __shfl_xor(wi, off);
    if (ov > val || (ov == val && owi < wi)) { val = ov; wi = owi; }
  }
  return e + wi;
}

__device__ inline int proc_pol(const float* __restrict__ x, int N, int sign,
                               const int* eL, int nE, const int* xL, int nX,
                               int* pk, int tid) {
  int n = nE < nX ? nE : nX;
  int tot = 0;
  for (int t = 0; t < n; ++t) {
    int dur = xL[t] - eL[t];
    if (dur <= MAX_SPIKE) {                    // negative dur kept (ref semantics)
      int pp = wave_argmax36(x, N, sign, eL[t], tid);
      if (tot < PEAK_CAP && tid == 0) pk[tot] = pp;
      ++tot;
    }
  }
  if (tot > PEAK_CAP) tot = PEAK_CAP;
  if (tid == 0) isort(pk, tot);                // ref sorts peaks
  return tot;
}

__global__ void k_finalize(const float* __restrict__ x, int N,
                           int* __restrict__ p, int* __restrict__ cand,
                           float* __restrict__ out, int OUT_K) {
  __shared__ int pe[PAIR_CAP], px[PAIR_CAP], ne[PAIR_CAP], nx[PAIR_CAP];
  __shared__ int cnt[4];
  __shared__ int pkP[PEAK_CAP], pkN[PEAK_CAP];
  __shared__ int nPk[2];
  int tid = threadIdx.x;                        // blockDim = 64 (one wave)
  float thr = __int_as_float(p[P_THR]);
  int nC = p[P_CANDN]; if (nC > CAND_CAP) nC = CAND_CAP;
  if (tid < 4) cnt[tid] = 0;
  __syncthreads();
  if (tid == 0) isort(cand, nC);                // sort candidate indices
  __syncthreads();
  // pair (p,p+1) processed exactly once: from candidate p (right pair),
  // or from candidate p+1 iff p not a candidate.
  for (int k = tid; k < nC; k += 64) {
    int c = cand[k];
    bool prevAdj = (k > 0) && (cand[k - 1] == c - 1);
    if (c > 0 && !prevAdj) eval_pair(x, c - 1, thr, pe, px, ne, nx, cnt);
    if (c <= N - 2) eval_pair(x, c, thr, pe, px, ne, nx, cnt);
  }
  __syncthreads();
  int nPE = min(cnt[0], PAIR_CAP), nPX = min(cnt[1], PAIR_CAP);
  int nNE = min(cnt[2], PAIR_CAP), nNX = min(cnt[3], PAIR_CAP);
  if (tid == 0) { isort(pe, nPE); isort(px, nPX); }
  else if (tid == 1) { isort(ne, nNE); isort(nx, nNX); }
  __syncthreads();
  int t0 = proc_pol(x, N, +1, pe, nPE, px, nPX, pkP, tid);
  int t1 = proc_pol(x, N, -1, ne, nNE, nx, nNX, pkN, tid);
  if (tid == 0) { nPk[0] = t0; nPk[1] = t1; }
  __syncthreads();
  for (int j = tid; j < nPk[0]; j += 64) out[j] = (float)pkP[j];
  for (int j = tid; j < nPk[1]; j += 64) out[OUT_K + j] = (float)pkN[j];
}

extern "C" void kernel_launch(void* const* d_in, const int* in_sizes, int n_in,
                              void* d_out, int out_size, void* d_ws, size_t ws_size,
                              hipStream_t stream) {
  const float* x = (const float*)d_in[0];
  int N = in_sizes[0];
  float* out = (float*)d_out;
  char* ws = (char*)d_ws;

  int* shist  = (int*)(ws + WS_SHIST);
  int* histA  = (int*)(ws + WS_HISTA);
  int* histB  = (int*)(ws + WS_HISTB);
  int* params = (int*)(ws + WS_PARAMS);
  int* cand   = (int*)(ws + WS_CAND);
  int* list   = (int*)(ws + WS_LIST);

  long long k1 = (long long)(N / 2) - 1;
  long long k2 = (long long)(N / 2);
  int OUT_K = (out_size - 1) / 2;  // 65536

  int zInts = WS_ZERO_BYTES / 4;
  k_zero<<<(zInts + 255) / 256, 256, 0, stream>>>((int*)ws, zInts);
  k_fillpad<<<(2 * OUT_K + 255) / 256, 256, 0, stream>>>(out, 2 * OUT_K);
  k_sample<<<64, 256, 0, stream>>>(x, N, shist);
  k_bandsel<<<1, 256, 0, stream>>>(shist, params);
  k_main<<<2048, 256, 0, stream>>>(x, N, params, list, cand);
  k_stageA<<<AB_BLOCKS, 256, 0, stream>>>(list, params, histA, k1, k2);
  k_stageB<<<AB_BLOCKS, 256, 0, stream>>>(list, params, histB, out + 2 * OUT_K);
  k_finalize<<<1, 64, 0, stream>>>(x, N, params, cand, out, OUT_K);
}